// Round 1
// baseline (421.117 us; speedup 1.0000x reference)
//
#include <hip/hip_runtime.h>

#define N_NODES 50000
#define N_EDGES 800000
#define IN_FT 256
#define OUT_FT 128

// ---------------- GEMM: seq_fts[n][o] = sum_i seq[n][i] * W[o][i] ----------
// fp32 vector-ALU tiled GEMM. BM=64 rows/block, BN=128 (all outputs), BK=32.
#define BM 64
#define BK 32
#define APAD 4   // keeps As rows 16B-aligned for ds_read_b128, breaks pow2 stride

__global__ __launch_bounds__(256) void k_gemm(const float* __restrict__ seq,
                                              const float* __restrict__ W,
                                              float* __restrict__ seq_fts) {
    __shared__ float As[BK][BM + APAD];   // transposed: As[k][m]
    __shared__ float Bs[BK][OUT_FT];      // Bs[k][o]
    const int t  = threadIdx.x;
    const int m0 = blockIdx.x * BM;

    const int tm = t >> 4;   // 0..15 -> 4 rows each
    const int to = t & 15;   // 0..15 -> 8 outs each

    float acc[4][8];
#pragma unroll
    for (int i = 0; i < 4; ++i)
#pragma unroll
        for (int j = 0; j < 8; ++j) acc[i][j] = 0.f;

    const int ar = t >> 3;        // 0..31 (row; +32 for second half)
    const int ak = (t & 7) * 4;   // k offset within tile
    const int bo = t >> 1;        // 0..127 (W row)
    const int bk = (t & 1) * 16;  // k offset within tile

    for (int k0 = 0; k0 < IN_FT; k0 += BK) {
#pragma unroll
        for (int h = 0; h < 2; ++h) {
            int row = ar + 32 * h;
            int m   = m0 + row;
            float4 v = make_float4(0.f, 0.f, 0.f, 0.f);
            if (m < N_NODES)
                v = *(const float4*)&seq[(size_t)m * IN_FT + k0 + ak];
            As[ak + 0][row] = v.x;
            As[ak + 1][row] = v.y;
            As[ak + 2][row] = v.z;
            As[ak + 3][row] = v.w;
        }
#pragma unroll
        for (int c = 0; c < 4; ++c) {
            float4 v = *(const float4*)&W[(size_t)bo * IN_FT + k0 + bk + c * 4];
            Bs[bk + c * 4 + 0][bo] = v.x;
            Bs[bk + c * 4 + 1][bo] = v.y;
            Bs[bk + c * 4 + 2][bo] = v.z;
            Bs[bk + c * 4 + 3][bo] = v.w;
        }
        __syncthreads();
#pragma unroll
        for (int k = 0; k < BK; ++k) {
            float a[4], b[8];
            *(float4*)a      = *(const float4*)&As[k][tm * 4];
            *(float4*)&b[0]  = *(const float4*)&Bs[k][to * 8];
            *(float4*)&b[4]  = *(const float4*)&Bs[k][to * 8 + 4];
#pragma unroll
            for (int i = 0; i < 4; ++i)
#pragma unroll
                for (int j = 0; j < 8; ++j)
                    acc[i][j] += a[i] * b[j];
        }
        __syncthreads();
    }
#pragma unroll
    for (int i = 0; i < 4; ++i) {
        int m = m0 + tm * 4 + i;
        if (m < N_NODES) {
            float4 v0 = make_float4(acc[i][0], acc[i][1], acc[i][2], acc[i][3]);
            float4 v1 = make_float4(acc[i][4], acc[i][5], acc[i][6], acc[i][7]);
            *(float4*)&seq_fts[(size_t)m * OUT_FT + to * 8]     = v0;
            *(float4*)&seq_fts[(size_t)m * OUT_FT + to * 8 + 4] = v1;
        }
    }
}

// ---------------- CSR build ----------------
__global__ void k_zero(int* __restrict__ counts, int n) {
    int i = blockIdx.x * blockDim.x + threadIdx.x;
    if (i < n) counts[i] = 0;
}

__global__ void k_hist(const int* __restrict__ dst, int* __restrict__ counts) {
    int e = blockIdx.x * blockDim.x + threadIdx.x;
    if (e < N_EDGES) atomicAdd(&counts[dst[e]], 1);
}

// single-block exclusive scan over counts[0..N_NODES) -> row_ptr, cursor
#define SCAN_T 1024
#define SCAN_C 49   // 1024*49 = 50176 >= 50000
__global__ __launch_bounds__(SCAN_T) void k_scan(const int* __restrict__ counts,
                                                 int* __restrict__ row_ptr,
                                                 int* __restrict__ cursor) {
    __shared__ int lds[SCAN_T];
    int tid  = threadIdx.x;
    int base = tid * SCAN_C;
    int sum  = 0;
    for (int j = 0; j < SCAN_C; ++j) {
        int idx = base + j;
        if (idx < N_NODES) sum += counts[idx];
    }
    lds[tid] = sum;
    __syncthreads();
    for (int s = 1; s < SCAN_T; s <<= 1) {
        int v = (tid >= s) ? lds[tid - s] : 0;
        __syncthreads();
        lds[tid] += v;
        __syncthreads();
    }
    int run = lds[tid] - sum;   // exclusive prefix of this thread's chunk
    for (int j = 0; j < SCAN_C; ++j) {
        int idx = base + j;
        if (idx < N_NODES) {
            row_ptr[idx] = run;
            cursor[idx]  = run;
            run += counts[idx];
        }
    }
    if (tid == SCAN_T - 1) row_ptr[N_NODES] = lds[SCAN_T - 1];
}

__global__ void k_fill(const int* __restrict__ src, const int* __restrict__ dst,
                       const float* __restrict__ val, int* __restrict__ cursor,
                       int* __restrict__ csr_src, float* __restrict__ csr_val) {
    int e = blockIdx.x * blockDim.x + threadIdx.x;
    if (e < N_EDGES) {
        int d   = dst[e];
        int pos = atomicAdd(&cursor[d], 1);
        csr_src[pos] = src[e];
        csr_val[pos] = val[e];
    }
}

// ---------------- gather + bias + PReLU ----------------
__global__ __launch_bounds__(OUT_FT) void k_gather(const float* __restrict__ seq_fts,
                                                   const int* __restrict__ row_ptr,
                                                   const int* __restrict__ csr_src,
                                                   const float* __restrict__ csr_val,
                                                   const float* __restrict__ bias,
                                                   const float* __restrict__ prelu_a,
                                                   float* __restrict__ out) {
    const int n = blockIdx.x;
    const int f = threadIdx.x;
    const int s0 = row_ptr[n];
    const int s1 = row_ptr[n + 1];
    float acc = 0.f;
    int j = s0;
    for (; j + 3 < s1; j += 4) {
        int   a0 = csr_src[j],     a1 = csr_src[j + 1];
        int   a2 = csr_src[j + 2], a3 = csr_src[j + 3];
        float v0 = csr_val[j],     v1 = csr_val[j + 1];
        float v2 = csr_val[j + 2], v3 = csr_val[j + 3];
        acc += v0 * seq_fts[(size_t)a0 * OUT_FT + f];
        acc += v1 * seq_fts[(size_t)a1 * OUT_FT + f];
        acc += v2 * seq_fts[(size_t)a2 * OUT_FT + f];
        acc += v3 * seq_fts[(size_t)a3 * OUT_FT + f];
    }
    for (; j < s1; ++j)
        acc += csr_val[j] * seq_fts[(size_t)csr_src[j] * OUT_FT + f];
    float x = acc + bias[f];
    float a = prelu_a[0];
    out[(size_t)n * OUT_FT + f] = (x >= 0.f) ? x : a * x;
}

extern "C" void kernel_launch(void* const* d_in, const int* in_sizes, int n_in,
                              void* d_out, int out_size, void* d_ws, size_t ws_size,
                              hipStream_t stream) {
    const float* seq      = (const float*)d_in[0];
    const int*   edge_src = (const int*)d_in[1];
    const int*   edge_dst = (const int*)d_in[2];
    const float* edge_val = (const float*)d_in[3];
    const float* W        = (const float*)d_in[4];
    const float* bias     = (const float*)d_in[5];
    const float* prelu_a  = (const float*)d_in[6];
    float* out = (float*)d_out;

    char* ws = (char*)d_ws;
    size_t off = 0;
    auto alloc = [&](size_t bytes) {
        void* p = ws + off;
        off = (off + bytes + 255) & ~(size_t)255;
        return p;
    };
    float* seq_fts = (float*)alloc((size_t)N_NODES * OUT_FT * sizeof(float));
    int*   row_ptr = (int*)alloc((size_t)(N_NODES + 1) * sizeof(int));
    int*   cursor  = (int*)alloc((size_t)N_NODES * sizeof(int));
    int*   counts  = (int*)alloc((size_t)N_NODES * sizeof(int));
    int*   csr_src = (int*)alloc((size_t)N_EDGES * sizeof(int));
    float* csr_val = (float*)alloc((size_t)N_EDGES * sizeof(float));
    (void)ws_size; (void)in_sizes; (void)n_in; (void)out_size;

    k_gemm<<<(N_NODES + BM - 1) / BM, 256, 0, stream>>>(seq, W, seq_fts);
    k_zero<<<(N_NODES + 255) / 256, 256, 0, stream>>>(counts, N_NODES);
    k_hist<<<(N_EDGES + 255) / 256, 256, 0, stream>>>(edge_dst, counts);
    k_scan<<<1, SCAN_T, 0, stream>>>(counts, row_ptr, cursor);
    k_fill<<<(N_EDGES + 255) / 256, 256, 0, stream>>>(edge_src, edge_dst, edge_val,
                                                      cursor, csr_src, csr_val);
    k_gather<<<N_NODES, OUT_FT, 0, stream>>>(seq_fts, row_ptr, csr_src, csr_val,
                                             bias, prelu_a, out);
}

// Round 2
// 305.352 us; speedup vs baseline: 1.3791x; 1.3791x over previous
//
#include <hip/hip_runtime.h>

#define N_NODES 50000
#define N_EDGES 800000
#define IN_FT 256
#define OUT_FT 128

// ---------------- GEMM: seq_fts[n][o] = sum_i seq[n][i] * W[o][i] ----------
#define BM 64
#define BK 32
#define APAD 4

__global__ __launch_bounds__(256) void k_gemm(const float* __restrict__ seq,
                                              const float* __restrict__ W,
                                              float* __restrict__ seq_fts) {
    __shared__ float As[BK][BM + APAD];   // transposed: As[k][m]
    __shared__ float Bs[BK][OUT_FT];      // Bs[k][o]
    const int t  = threadIdx.x;
    const int m0 = blockIdx.x * BM;

    const int tm = t >> 4;   // 0..15 -> 4 rows each
    const int to = t & 15;   // 0..15 -> 8 outs each

    float acc[4][8];
#pragma unroll
    for (int i = 0; i < 4; ++i)
#pragma unroll
        for (int j = 0; j < 8; ++j) acc[i][j] = 0.f;

    const int ar = t >> 3;        // 0..31 (row; +32 for second half)
    const int ak = (t & 7) * 4;   // k offset within tile
    const int bo = t >> 1;        // 0..127 (W row)
    const int bk = (t & 1) * 16;  // k offset within tile

    for (int k0 = 0; k0 < IN_FT; k0 += BK) {
#pragma unroll
        for (int h = 0; h < 2; ++h) {
            int row = ar + 32 * h;
            int m   = m0 + row;
            float4 v = make_float4(0.f, 0.f, 0.f, 0.f);
            if (m < N_NODES)
                v = *(const float4*)&seq[(size_t)m * IN_FT + k0 + ak];
            As[ak + 0][row] = v.x;
            As[ak + 1][row] = v.y;
            As[ak + 2][row] = v.z;
            As[ak + 3][row] = v.w;
        }
#pragma unroll
        for (int c = 0; c < 4; ++c) {
            float4 v = *(const float4*)&W[(size_t)bo * IN_FT + k0 + bk + c * 4];
            Bs[bk + c * 4 + 0][bo] = v.x;
            Bs[bk + c * 4 + 1][bo] = v.y;
            Bs[bk + c * 4 + 2][bo] = v.z;
            Bs[bk + c * 4 + 3][bo] = v.w;
        }
        __syncthreads();
#pragma unroll
        for (int k = 0; k < BK; ++k) {
            float a[4], b[8];
            *(float4*)a      = *(const float4*)&As[k][tm * 4];
            *(float4*)&b[0]  = *(const float4*)&Bs[k][to * 8];
            *(float4*)&b[4]  = *(const float4*)&Bs[k][to * 8 + 4];
#pragma unroll
            for (int i = 0; i < 4; ++i)
#pragma unroll
                for (int j = 0; j < 8; ++j)
                    acc[i][j] += a[i] * b[j];
        }
        __syncthreads();
    }
#pragma unroll
    for (int i = 0; i < 4; ++i) {
        int m = m0 + tm * 4 + i;
        if (m < N_NODES) {
            float4 v0 = make_float4(acc[i][0], acc[i][1], acc[i][2], acc[i][3]);
            float4 v1 = make_float4(acc[i][4], acc[i][5], acc[i][6], acc[i][7]);
            *(float4*)&seq_fts[(size_t)m * OUT_FT + to * 8]     = v0;
            *(float4*)&seq_fts[(size_t)m * OUT_FT + to * 8 + 4] = v1;
        }
    }
}

// ---------------- CSR build ----------------
__global__ void k_zero(int* __restrict__ counts, int n) {
    int i = blockIdx.x * blockDim.x + threadIdx.x;
    if (i < n) counts[i] = 0;
}

__global__ void k_hist(const int* __restrict__ dst, int* __restrict__ counts) {
    int e = blockIdx.x * blockDim.x + threadIdx.x;
    if (e < N_EDGES) atomicAdd(&counts[dst[e]], 1);
}

// ---- device-wide exclusive scan over counts[0..N_NODES) in 3 kernels ----
#define SCAN_B 256
#define NBLK ((N_NODES + SCAN_B - 1) / SCAN_B)   // 196

__global__ __launch_bounds__(SCAN_B) void k_psum(const int* __restrict__ counts,
                                                 int* __restrict__ part) {
    int i = blockIdx.x * SCAN_B + threadIdx.x;
    int v = (i < N_NODES) ? counts[i] : 0;
#pragma unroll
    for (int s = 32; s > 0; s >>= 1) v += __shfl_down(v, s, 64);
    __shared__ int w[4];
    if ((threadIdx.x & 63) == 0) w[threadIdx.x >> 6] = v;
    __syncthreads();
    if (threadIdx.x == 0) part[blockIdx.x] = w[0] + w[1] + w[2] + w[3];
}

__global__ __launch_bounds__(SCAN_B) void k_scanp(const int* __restrict__ part,
                                                  int* __restrict__ partoff,
                                                  int* __restrict__ row_ptr) {
    __shared__ int lds[SCAN_B];
    int tid = threadIdx.x;
    int v = (tid < NBLK) ? part[tid] : 0;
    lds[tid] = v;
    __syncthreads();
#pragma unroll
    for (int s = 1; s < SCAN_B; s <<= 1) {
        int t2 = (tid >= s) ? lds[tid - s] : 0;
        __syncthreads();
        lds[tid] += t2;
        __syncthreads();
    }
    if (tid < NBLK) partoff[tid] = lds[tid] - v;   // exclusive
    if (tid == SCAN_B - 1) row_ptr[N_NODES] = lds[SCAN_B - 1];
}

__global__ __launch_bounds__(SCAN_B) void k_wrscan(const int* __restrict__ counts,
                                                   const int* __restrict__ partoff,
                                                   int* __restrict__ row_ptr,
                                                   int* __restrict__ cursor) {
    __shared__ int lds[SCAN_B];
    int tid = threadIdx.x;
    int i = blockIdx.x * SCAN_B + tid;
    int v = (i < N_NODES) ? counts[i] : 0;
    lds[tid] = v;
    __syncthreads();
#pragma unroll
    for (int s = 1; s < SCAN_B; s <<= 1) {
        int t2 = (tid >= s) ? lds[tid - s] : 0;
        __syncthreads();
        lds[tid] += t2;
        __syncthreads();
    }
    if (i < N_NODES) {
        int p = partoff[blockIdx.x] + lds[tid] - v;
        row_ptr[i] = p;
        cursor[i]  = p;
    }
}

__global__ void k_fill(const int* __restrict__ src, const int* __restrict__ dst,
                       const float* __restrict__ val, int* __restrict__ cursor,
                       int* __restrict__ csr_src, float* __restrict__ csr_val) {
    int e = blockIdx.x * blockDim.x + threadIdx.x;
    if (e < N_EDGES) {
        int d   = dst[e];
        int pos = atomicAdd(&cursor[d], 1);
        csr_src[pos] = src[e];
        csr_val[pos] = val[e];
    }
}

// ---------------- gather + bias + PReLU ----------------
__global__ __launch_bounds__(OUT_FT) void k_gather(const float* __restrict__ seq_fts,
                                                   const int* __restrict__ row_ptr,
                                                   const int* __restrict__ csr_src,
                                                   const float* __restrict__ csr_val,
                                                   const float* __restrict__ bias,
                                                   const float* __restrict__ prelu_a,
                                                   float* __restrict__ out) {
    const int n = blockIdx.x;
    const int f = threadIdx.x;
    const int s0 = row_ptr[n];
    const int s1 = row_ptr[n + 1];
    float acc = 0.f;
    int j = s0;
    for (; j + 3 < s1; j += 4) {
        int   a0 = csr_src[j],     a1 = csr_src[j + 1];
        int   a2 = csr_src[j + 2], a3 = csr_src[j + 3];
        float v0 = csr_val[j],     v1 = csr_val[j + 1];
        float v2 = csr_val[j + 2], v3 = csr_val[j + 3];
        acc += v0 * seq_fts[(size_t)a0 * OUT_FT + f];
        acc += v1 * seq_fts[(size_t)a1 * OUT_FT + f];
        acc += v2 * seq_fts[(size_t)a2 * OUT_FT + f];
        acc += v3 * seq_fts[(size_t)a3 * OUT_FT + f];
    }
    for (; j < s1; ++j)
        acc += csr_val[j] * seq_fts[(size_t)csr_src[j] * OUT_FT + f];
    float x = acc + bias[f];
    float a = prelu_a[0];
    out[(size_t)n * OUT_FT + f] = (x >= 0.f) ? x : a * x;
}

extern "C" void kernel_launch(void* const* d_in, const int* in_sizes, int n_in,
                              void* d_out, int out_size, void* d_ws, size_t ws_size,
                              hipStream_t stream) {
    const float* seq      = (const float*)d_in[0];
    const int*   edge_src = (const int*)d_in[1];
    const int*   edge_dst = (const int*)d_in[2];
    const float* edge_val = (const float*)d_in[3];
    const float* W        = (const float*)d_in[4];
    const float* bias     = (const float*)d_in[5];
    const float* prelu_a  = (const float*)d_in[6];
    float* out = (float*)d_out;

    char* ws = (char*)d_ws;
    size_t off = 0;
    auto alloc = [&](size_t bytes) {
        void* p = ws + off;
        off = (off + bytes + 255) & ~(size_t)255;
        return p;
    };
    float* seq_fts = (float*)alloc((size_t)N_NODES * OUT_FT * sizeof(float));
    int*   row_ptr = (int*)alloc((size_t)(N_NODES + 1) * sizeof(int));
    int*   cursor  = (int*)alloc((size_t)N_NODES * sizeof(int));
    int*   counts  = (int*)alloc((size_t)N_NODES * sizeof(int));
    int*   part    = (int*)alloc((size_t)NBLK * sizeof(int));
    int*   partoff = (int*)alloc((size_t)NBLK * sizeof(int));
    int*   csr_src = (int*)alloc((size_t)N_EDGES * sizeof(int));
    float* csr_val = (float*)alloc((size_t)N_EDGES * sizeof(float));
    (void)ws_size; (void)in_sizes; (void)n_in; (void)out_size;

    k_gemm<<<(N_NODES + BM - 1) / BM, 256, 0, stream>>>(seq, W, seq_fts);
    k_zero<<<(N_NODES + 255) / 256, 256, 0, stream>>>(counts, N_NODES);
    k_hist<<<(N_EDGES + 255) / 256, 256, 0, stream>>>(edge_dst, counts);
    k_psum<<<NBLK, SCAN_B, 0, stream>>>(counts, part);
    k_scanp<<<1, SCAN_B, 0, stream>>>(part, partoff, row_ptr);
    k_wrscan<<<NBLK, SCAN_B, 0, stream>>>(counts, partoff, row_ptr, cursor);
    k_fill<<<(N_EDGES + 255) / 256, 256, 0, stream>>>(edge_src, edge_dst, edge_val,
                                                      cursor, csr_src, csr_val);
    k_gather<<<N_NODES, OUT_FT, 0, stream>>>(seq_fts, row_ptr, csr_src, csr_val,
                                             bias, prelu_a, out);
}

// Round 3
// 269.378 us; speedup vs baseline: 1.5633x; 1.1335x over previous
//
#include <hip/hip_runtime.h>
#include <hip/hip_bf16.h>

#define N_NODES 50000
#define N_EDGES 800000
#define IN_FT 256
#define OUT_FT 128

typedef __bf16 bf16;
typedef __attribute__((ext_vector_type(8))) __bf16 bf16x8;
typedef __attribute__((ext_vector_type(4))) __bf16 bf16x4;
typedef __attribute__((ext_vector_type(4))) float floatx4;

// ---------------- GEMM: seq_fts[n][o] = sum_i seq[n][i] * W[o][i] ----------
// bf16 MFMA (16x16x32). Block = 256 thr = 4 waves; 64 M-rows per block, all
// 128 N-cols. W (128x256) staged once per block into LDS as bf16, row padded
// to 264 elems (528 B) -> ds_read_b128 start-banks spread 4*(l16+q)%32, so
// each consecutive-8-lane group covers all 32 banks once (conflict-free).
#define WP 264

__global__ __launch_bounds__(256) void k_gemm(const float* __restrict__ seq,
                                              const float* __restrict__ W,
                                              float* __restrict__ seq_fts) {
    __shared__ bf16 Wlds[128 * WP];
    const int t = threadIdx.x;

    // ---- stage W -> LDS (bf16), 2 threads per row ----
    {
        const int row  = t >> 1;
        const int half = (t & 1) * 128;
        const float* wr = W + (size_t)row * IN_FT + half;
        bf16* dst = Wlds + row * WP + half;
#pragma unroll
        for (int c = 0; c < 32; ++c) {
            float4 v = *(const float4*)(wr + c * 4);
            bf16x4 b;
            b[0] = (bf16)v.x; b[1] = (bf16)v.y; b[2] = (bf16)v.z; b[3] = (bf16)v.w;
            *(bf16x4*)(dst + c * 4) = b;
        }
    }

    const int lane = t & 63;
    const int wave = t >> 6;
    const int quad = lane >> 4;
    const int l16  = lane & 15;

    // ---- A fragments: lane holds A[m=l16][k=quad*8+j], j=0..7, per K-step ----
    int arow = blockIdx.x * 64 + wave * 16 + l16;
    if (arow >= N_NODES) arow = 0;            // clamped; stores are guarded
    const float* ap = seq + (size_t)arow * IN_FT + quad * 8;
    bf16x8 afr[8];
#pragma unroll
    for (int s = 0; s < 8; ++s) {
        float4 v0 = *(const float4*)(ap + s * 32);
        float4 v1 = *(const float4*)(ap + s * 32 + 4);
        bf16x8 a;
        a[0] = (bf16)v0.x; a[1] = (bf16)v0.y; a[2] = (bf16)v0.z; a[3] = (bf16)v0.w;
        a[4] = (bf16)v1.x; a[5] = (bf16)v1.y; a[6] = (bf16)v1.z; a[7] = (bf16)v1.w;
        afr[s] = a;
    }
    __syncthreads();

    const int mbase = blockIdx.x * 64 + wave * 16;
#pragma unroll
    for (int tt = 0; tt < 8; ++tt) {
        floatx4 acc = {0.f, 0.f, 0.f, 0.f};
        const bf16* bp = Wlds + (tt * 16 + l16) * WP + quad * 8;
#pragma unroll
        for (int s = 0; s < 8; ++s) {
            bf16x8 bfr = *(const bf16x8*)(bp + s * 32);
            acc = __builtin_amdgcn_mfma_f32_16x16x32_bf16(afr[s], bfr, acc, 0, 0, 0);
        }
#pragma unroll
        for (int r = 0; r < 4; ++r) {
            int m = mbase + quad * 4 + r;   // C/D: row = quad*4+reg, col = l16
            if (m < N_NODES)
                seq_fts[(size_t)m * OUT_FT + tt * 16 + l16] = acc[r];
        }
    }
}

// ---------------- CSR build ----------------
__global__ void k_zero(int* __restrict__ counts, int n) {
    int i = blockIdx.x * blockDim.x + threadIdx.x;
    if (i < n) counts[i] = 0;
}

__global__ void k_hist(const int* __restrict__ dst, int* __restrict__ counts) {
    int e = blockIdx.x * blockDim.x + threadIdx.x;
    if (e < N_EDGES) atomicAdd(&counts[dst[e]], 1);
}

// ---- device-wide exclusive scan over counts[0..N_NODES) in 3 kernels ----
#define SCAN_B 256
#define NBLK ((N_NODES + SCAN_B - 1) / SCAN_B)   // 196

__global__ __launch_bounds__(SCAN_B) void k_psum(const int* __restrict__ counts,
                                                 int* __restrict__ part) {
    int i = blockIdx.x * SCAN_B + threadIdx.x;
    int v = (i < N_NODES) ? counts[i] : 0;
#pragma unroll
    for (int s = 32; s > 0; s >>= 1) v += __shfl_down(v, s, 64);
    __shared__ int w[4];
    if ((threadIdx.x & 63) == 0) w[threadIdx.x >> 6] = v;
    __syncthreads();
    if (threadIdx.x == 0) part[blockIdx.x] = w[0] + w[1] + w[2] + w[3];
}

__global__ __launch_bounds__(SCAN_B) void k_scanp(const int* __restrict__ part,
                                                  int* __restrict__ partoff,
                                                  int* __restrict__ row_ptr) {
    __shared__ int lds[SCAN_B];
    int tid = threadIdx.x;
    int v = (tid < NBLK) ? part[tid] : 0;
    lds[tid] = v;
    __syncthreads();
#pragma unroll
    for (int s = 1; s < SCAN_B; s <<= 1) {
        int t2 = (tid >= s) ? lds[tid - s] : 0;
        __syncthreads();
        lds[tid] += t2;
        __syncthreads();
    }
    if (tid < NBLK) partoff[tid] = lds[tid] - v;   // exclusive
    if (tid == SCAN_B - 1) row_ptr[N_NODES] = lds[SCAN_B - 1];
}

__global__ __launch_bounds__(SCAN_B) void k_wrscan(const int* __restrict__ counts,
                                                   const int* __restrict__ partoff,
                                                   int* __restrict__ row_ptr,
                                                   int* __restrict__ cursor) {
    __shared__ int lds[SCAN_B];
    int tid = threadIdx.x;
    int i = blockIdx.x * SCAN_B + tid;
    int v = (i < N_NODES) ? counts[i] : 0;
    lds[tid] = v;
    __syncthreads();
#pragma unroll
    for (int s = 1; s < SCAN_B; s <<= 1) {
        int t2 = (tid >= s) ? lds[tid - s] : 0;
        __syncthreads();
        lds[tid] += t2;
        __syncthreads();
    }
    if (i < N_NODES) {
        int p = partoff[blockIdx.x] + lds[tid] - v;
        row_ptr[i] = p;
        cursor[i]  = p;
    }
}

// packed (src, val) -> ONE scattered 8B store per edge (was two 4B stores to
// two arrays -> halves scattered sector traffic)
__global__ void k_fill(const int* __restrict__ src, const int* __restrict__ dst,
                       const float* __restrict__ val, int* __restrict__ cursor,
                       int2* __restrict__ csr_ev) {
    int e = blockIdx.x * blockDim.x + threadIdx.x;
    if (e < N_EDGES) {
        int d   = dst[e];
        int pos = atomicAdd(&cursor[d], 1);
        csr_ev[pos] = make_int2(src[e], __float_as_int(val[e]));
    }
}

// ---------------- gather + bias + PReLU ----------------
__global__ __launch_bounds__(OUT_FT) void k_gather(const float* __restrict__ seq_fts,
                                                   const int* __restrict__ row_ptr,
                                                   const int2* __restrict__ csr_ev,
                                                   const float* __restrict__ bias,
                                                   const float* __restrict__ prelu_a,
                                                   float* __restrict__ out) {
    const int n = blockIdx.x;
    const int f = threadIdx.x;
    const int s0 = row_ptr[n];
    const int s1 = row_ptr[n + 1];
    float acc = 0.f;
    int j = s0;
    for (; j + 3 < s1; j += 4) {
        int2 e0 = csr_ev[j];
        int2 e1 = csr_ev[j + 1];
        int2 e2 = csr_ev[j + 2];
        int2 e3 = csr_ev[j + 3];
        acc += __int_as_float(e0.y) * seq_fts[(size_t)e0.x * OUT_FT + f];
        acc += __int_as_float(e1.y) * seq_fts[(size_t)e1.x * OUT_FT + f];
        acc += __int_as_float(e2.y) * seq_fts[(size_t)e2.x * OUT_FT + f];
        acc += __int_as_float(e3.y) * seq_fts[(size_t)e3.x * OUT_FT + f];
    }
    for (; j < s1; ++j) {
        int2 e0 = csr_ev[j];
        acc += __int_as_float(e0.y) * seq_fts[(size_t)e0.x * OUT_FT + f];
    }
    float x = acc + bias[f];
    float a = prelu_a[0];
    out[(size_t)n * OUT_FT + f] = (x >= 0.f) ? x : a * x;
}

extern "C" void kernel_launch(void* const* d_in, const int* in_sizes, int n_in,
                              void* d_out, int out_size, void* d_ws, size_t ws_size,
                              hipStream_t stream) {
    const float* seq      = (const float*)d_in[0];
    const int*   edge_src = (const int*)d_in[1];
    const int*   edge_dst = (const int*)d_in[2];
    const float* edge_val = (const float*)d_in[3];
    const float* W        = (const float*)d_in[4];
    const float* bias     = (const float*)d_in[5];
    const float* prelu_a  = (const float*)d_in[6];
    float* out = (float*)d_out;

    char* ws = (char*)d_ws;
    size_t off = 0;
    auto alloc = [&](size_t bytes) {
        void* p = ws + off;
        off = (off + bytes + 255) & ~(size_t)255;
        return p;
    };
    float* seq_fts = (float*)alloc((size_t)N_NODES * OUT_FT * sizeof(float));
    int*   row_ptr = (int*)alloc((size_t)(N_NODES + 1) * sizeof(int));
    int*   cursor  = (int*)alloc((size_t)N_NODES * sizeof(int));
    int*   counts  = (int*)alloc((size_t)N_NODES * sizeof(int));
    int*   part    = (int*)alloc((size_t)NBLK * sizeof(int));
    int*   partoff = (int*)alloc((size_t)NBLK * sizeof(int));
    int2*  csr_ev  = (int2*)alloc((size_t)N_EDGES * sizeof(int2));
    (void)ws_size; (void)in_sizes; (void)n_in; (void)out_size;

    k_gemm<<<(N_NODES + 63) / 64, 256, 0, stream>>>(seq, W, seq_fts);
    k_zero<<<(N_NODES + 255) / 256, 256, 0, stream>>>(counts, N_NODES);
    k_hist<<<(N_EDGES + 255) / 256, 256, 0, stream>>>(edge_dst, counts);
    k_psum<<<NBLK, SCAN_B, 0, stream>>>(counts, part);
    k_scanp<<<1, SCAN_B, 0, stream>>>(part, partoff, row_ptr);
    k_wrscan<<<NBLK, SCAN_B, 0, stream>>>(counts, partoff, row_ptr, cursor);
    k_fill<<<(N_EDGES + 255) / 256, 256, 0, stream>>>(edge_src, edge_dst, edge_val,
                                                      cursor, csr_ev);
    k_gather<<<N_NODES, OUT_FT, 0, stream>>>(seq_fts, row_ptr, csr_ev,
                                             bias, prelu_a, out);
}

// Round 4
// 247.662 us; speedup vs baseline: 1.7004x; 1.0877x over previous
//
#include <hip/hip_runtime.h>
#include <hip/hip_bf16.h>

#define N_NODES 50000
#define N_EDGES 800000
#define IN_FT 256
#define OUT_FT 128

typedef __bf16 bf16;
typedef __attribute__((ext_vector_type(8))) __bf16 bf16x8;
typedef __attribute__((ext_vector_type(4))) __bf16 bf16x4;
typedef __attribute__((ext_vector_type(4))) float floatx4;

static __device__ inline unsigned short f2bf_bits(float f) {
    unsigned u = __float_as_uint(f);
    return (unsigned short)((u + 0x7FFFu + ((u >> 16) & 1u)) >> 16);  // RTNE
}

// ---------------- GEMM: seq_fts[n][o] = sum_i seq[n][i] * W[o][i] ----------
// bf16 MFMA (16x16x32), output stored as bf16 (halves downstream gather bytes).
#define WP 264

__global__ __launch_bounds__(256) void k_gemm(const float* __restrict__ seq,
                                              const float* __restrict__ W,
                                              unsigned short* __restrict__ seq_fts) {
    __shared__ bf16 Wlds[128 * WP];
    const int t = threadIdx.x;

    // ---- stage W -> LDS (bf16), 2 threads per row ----
    {
        const int row  = t >> 1;
        const int half = (t & 1) * 128;
        const float* wr = W + (size_t)row * IN_FT + half;
        bf16* dst = Wlds + row * WP + half;
#pragma unroll
        for (int c = 0; c < 32; ++c) {
            float4 v = *(const float4*)(wr + c * 4);
            bf16x4 b;
            b[0] = (bf16)v.x; b[1] = (bf16)v.y; b[2] = (bf16)v.z; b[3] = (bf16)v.w;
            *(bf16x4*)(dst + c * 4) = b;
        }
    }

    const int lane = t & 63;
    const int wave = t >> 6;
    const int quad = lane >> 4;
    const int l16  = lane & 15;

    // ---- A fragments: lane holds A[m=l16][k=quad*8+j], j=0..7 ----
    int arow = blockIdx.x * 64 + wave * 16 + l16;
    if (arow >= N_NODES) arow = 0;            // clamped; stores are guarded
    const float* ap = seq + (size_t)arow * IN_FT + quad * 8;
    bf16x8 afr[8];
#pragma unroll
    for (int s = 0; s < 8; ++s) {
        float4 v0 = *(const float4*)(ap + s * 32);
        float4 v1 = *(const float4*)(ap + s * 32 + 4);
        bf16x8 a;
        a[0] = (bf16)v0.x; a[1] = (bf16)v0.y; a[2] = (bf16)v0.z; a[3] = (bf16)v0.w;
        a[4] = (bf16)v1.x; a[5] = (bf16)v1.y; a[6] = (bf16)v1.z; a[7] = (bf16)v1.w;
        afr[s] = a;
    }
    __syncthreads();

    const int mbase = blockIdx.x * 64 + wave * 16;
#pragma unroll
    for (int tt = 0; tt < 8; ++tt) {
        floatx4 acc = {0.f, 0.f, 0.f, 0.f};
        const bf16* bp = Wlds + (tt * 16 + l16) * WP + quad * 8;
#pragma unroll
        for (int s = 0; s < 8; ++s) {
            bf16x8 bfr = *(const bf16x8*)(bp + s * 32);
            acc = __builtin_amdgcn_mfma_f32_16x16x32_bf16(afr[s], bfr, acc, 0, 0, 0);
        }
#pragma unroll
        for (int r = 0; r < 4; ++r) {
            int m = mbase + quad * 4 + r;   // C/D: row = quad*4+reg, col = l16
            if (m < N_NODES)
                seq_fts[(size_t)m * OUT_FT + tt * 16 + l16] = f2bf_bits(acc[r]);
        }
    }
}

// ---------------- CSR build ----------------
__global__ void k_zero(int* __restrict__ counts, int n) {
    int i = blockIdx.x * blockDim.x + threadIdx.x;
    if (i < n) counts[i] = 0;
}

__global__ void k_hist(const int* __restrict__ dst, int* __restrict__ counts) {
    int e = blockIdx.x * blockDim.x + threadIdx.x;
    if (e < N_EDGES) atomicAdd(&counts[dst[e]], 1);
}

// ---- device-wide exclusive scan over counts[0..N_NODES) in 3 kernels ----
#define SCAN_B 256
#define NBLK ((N_NODES + SCAN_B - 1) / SCAN_B)   // 196

__global__ __launch_bounds__(SCAN_B) void k_psum(const int* __restrict__ counts,
                                                 int* __restrict__ part) {
    int i = blockIdx.x * SCAN_B + threadIdx.x;
    int v = (i < N_NODES) ? counts[i] : 0;
#pragma unroll
    for (int s = 32; s > 0; s >>= 1) v += __shfl_down(v, s, 64);
    __shared__ int w[4];
    if ((threadIdx.x & 63) == 0) w[threadIdx.x >> 6] = v;
    __syncthreads();
    if (threadIdx.x == 0) part[blockIdx.x] = w[0] + w[1] + w[2] + w[3];
}

__global__ __launch_bounds__(SCAN_B) void k_scanp(const int* __restrict__ part,
                                                  int* __restrict__ partoff,
                                                  int* __restrict__ row_ptr) {
    __shared__ int lds[SCAN_B];
    int tid = threadIdx.x;
    int v = (tid < NBLK) ? part[tid] : 0;
    lds[tid] = v;
    __syncthreads();
#pragma unroll
    for (int s = 1; s < SCAN_B; s <<= 1) {
        int t2 = (tid >= s) ? lds[tid - s] : 0;
        __syncthreads();
        lds[tid] += t2;
        __syncthreads();
    }
    if (tid < NBLK) partoff[tid] = lds[tid] - v;   // exclusive
    if (tid == SCAN_B - 1) row_ptr[N_NODES] = lds[SCAN_B - 1];
}

__global__ __launch_bounds__(SCAN_B) void k_wrscan(const int* __restrict__ counts,
                                                   const int* __restrict__ partoff,
                                                   int* __restrict__ row_ptr,
                                                   int* __restrict__ cursor) {
    __shared__ int lds[SCAN_B];
    int tid = threadIdx.x;
    int i = blockIdx.x * SCAN_B + tid;
    int v = (i < N_NODES) ? counts[i] : 0;
    lds[tid] = v;
    __syncthreads();
#pragma unroll
    for (int s = 1; s < SCAN_B; s <<= 1) {
        int t2 = (tid >= s) ? lds[tid - s] : 0;
        __syncthreads();
        lds[tid] += t2;
        __syncthreads();
    }
    if (i < N_NODES) {
        int p = partoff[blockIdx.x] + lds[tid] - v;
        row_ptr[i] = p;
        cursor[i]  = p;
    }
}

// packed edge record: low16 = src node id (<50000 fits u16), high16 = bf16(val)
// -> ONE scattered 4B store per edge.
__global__ void k_fill(const int* __restrict__ src, const int* __restrict__ dst,
                       const float* __restrict__ val, int* __restrict__ cursor,
                       unsigned* __restrict__ csr_ev) {
    int e = blockIdx.x * blockDim.x + threadIdx.x;
    if (e < N_EDGES) {
        int d   = dst[e];
        int pos = atomicAdd(&cursor[d], 1);
        unsigned w = (unsigned)(unsigned short)src[e]
                   | ((unsigned)f2bf_bits(val[e]) << 16);
        csr_ev[pos] = w;
    }
}

// ---------------- gather + bias + PReLU ----------------
// one wave per node; lane handles features {2*lane, 2*lane+1} -> one dword
// (bf16x2) gathered per edge per lane = 256 B/row, fully coalesced.
#define GW 4
__global__ __launch_bounds__(64 * GW) void k_gather(const unsigned* __restrict__ fts,
                                                    const int* __restrict__ row_ptr,
                                                    const unsigned* __restrict__ csr_ev,
                                                    const float* __restrict__ bias,
                                                    const float* __restrict__ prelu_a,
                                                    float* __restrict__ out) {
    const int wave = threadIdx.x >> 6;
    const int lane = threadIdx.x & 63;
    const int n = blockIdx.x * GW + wave;
    if (n >= N_NODES) return;
    const int s0 = row_ptr[n];
    const int s1 = row_ptr[n + 1];
    float acc0 = 0.f, acc1 = 0.f;
    int j = s0;
    for (; j + 3 < s1; j += 4) {
        unsigned w0 = csr_ev[j],     w1 = csr_ev[j + 1];
        unsigned w2 = csr_ev[j + 2], w3 = csr_ev[j + 3];
        unsigned p0 = fts[(w0 & 0xFFFFu) * 64u + lane];
        unsigned p1 = fts[(w1 & 0xFFFFu) * 64u + lane];
        unsigned p2 = fts[(w2 & 0xFFFFu) * 64u + lane];
        unsigned p3 = fts[(w3 & 0xFFFFu) * 64u + lane];
        float v0 = __uint_as_float(w0 & 0xFFFF0000u);
        float v1 = __uint_as_float(w1 & 0xFFFF0000u);
        float v2 = __uint_as_float(w2 & 0xFFFF0000u);
        float v3 = __uint_as_float(w3 & 0xFFFF0000u);
        acc0 += v0 * __uint_as_float(p0 << 16);
        acc1 += v0 * __uint_as_float(p0 & 0xFFFF0000u);
        acc0 += v1 * __uint_as_float(p1 << 16);
        acc1 += v1 * __uint_as_float(p1 & 0xFFFF0000u);
        acc0 += v2 * __uint_as_float(p2 << 16);
        acc1 += v2 * __uint_as_float(p2 & 0xFFFF0000u);
        acc0 += v3 * __uint_as_float(p3 << 16);
        acc1 += v3 * __uint_as_float(p3 & 0xFFFF0000u);
    }
    for (; j < s1; ++j) {
        unsigned w0 = csr_ev[j];
        unsigned p0 = fts[(w0 & 0xFFFFu) * 64u + lane];
        float v0 = __uint_as_float(w0 & 0xFFFF0000u);
        acc0 += v0 * __uint_as_float(p0 << 16);
        acc1 += v0 * __uint_as_float(p0 & 0xFFFF0000u);
    }
    float2 b = *(const float2*)&bias[lane * 2];
    float a = prelu_a[0];
    float x0 = acc0 + b.x;
    float x1 = acc1 + b.y;
    x0 = (x0 >= 0.f) ? x0 : a * x0;
    x1 = (x1 >= 0.f) ? x1 : a * x1;
    *(float2*)&out[(size_t)n * OUT_FT + lane * 2] = make_float2(x0, x1);
}

extern "C" void kernel_launch(void* const* d_in, const int* in_sizes, int n_in,
                              void* d_out, int out_size, void* d_ws, size_t ws_size,
                              hipStream_t stream) {
    const float* seq      = (const float*)d_in[0];
    const int*   edge_src = (const int*)d_in[1];
    const int*   edge_dst = (const int*)d_in[2];
    const float* edge_val = (const float*)d_in[3];
    const float* W        = (const float*)d_in[4];
    const float* bias     = (const float*)d_in[5];
    const float* prelu_a  = (const float*)d_in[6];
    float* out = (float*)d_out;

    char* ws = (char*)d_ws;
    size_t off = 0;
    auto alloc = [&](size_t bytes) {
        void* p = ws + off;
        off = (off + bytes + 255) & ~(size_t)255;
        return p;
    };
    unsigned short* seq_fts = (unsigned short*)alloc((size_t)N_NODES * OUT_FT * sizeof(unsigned short));
    int*   row_ptr = (int*)alloc((size_t)(N_NODES + 1) * sizeof(int));
    int*   cursor  = (int*)alloc((size_t)N_NODES * sizeof(int));
    int*   counts  = (int*)alloc((size_t)N_NODES * sizeof(int));
    int*   part    = (int*)alloc((size_t)NBLK * sizeof(int));
    int*   partoff = (int*)alloc((size_t)NBLK * sizeof(int));
    unsigned* csr_ev = (unsigned*)alloc((size_t)N_EDGES * sizeof(unsigned));
    (void)ws_size; (void)in_sizes; (void)n_in; (void)out_size;

    k_gemm<<<(N_NODES + 63) / 64, 256, 0, stream>>>(seq, W, seq_fts);
    k_zero<<<(N_NODES + 255) / 256, 256, 0, stream>>>(counts, N_NODES);
    k_hist<<<(N_EDGES + 255) / 256, 256, 0, stream>>>(edge_dst, counts);
    k_psum<<<NBLK, SCAN_B, 0, stream>>>(counts, part);
    k_scanp<<<1, SCAN_B, 0, stream>>>(part, partoff, row_ptr);
    k_wrscan<<<NBLK, SCAN_B, 0, stream>>>(counts, partoff, row_ptr, cursor);
    k_fill<<<(N_EDGES + 255) / 256, 256, 0, stream>>>(edge_src, edge_dst, edge_val,
                                                      cursor, csr_ev);
    k_gather<<<(N_NODES + GW - 1) / GW, 64 * GW, 0, stream>>>((const unsigned*)seq_fts,
                                                              row_ptr, csr_ev,
                                                              bias, prelu_a, out);
}